// Round 3
// baseline (148.323 us; speedup 1.0000x reference)
//
#include <hip/hip_runtime.h>
#include <hip/hip_bf16.h>

// Z[b,w,t] = sum_c Q[b,w,c] * (K[b,w+t,c] + bias[c,t])
// B=16, T=1024, C=128, K has 2T-1=2047 rows.
//
// Round 3: one fused GEMM per block via mfma_f32_32x32x16_bf16.
//   A = Q tile (32x128), B-rows = [96 K band rows | 64 bias^T rows] -> 5
//   32x32 output tiles, one per wave (320-thread blocks). Waves 0-2 produce
//   the S band -> LDS; waves 3-4 hold bias C in regs, gather S diag, store.
// Pre-pass converts Q,K->bf16 and bias->bf16-transposed in d_ws.

#define B_    16
#define T_    1024
#define C_    128
#define KT_   2047

#define BW    32
#define BT    64
#define SS_LD 98
#define NSLOT 3072   // 192 LDS rows * 16 chunks of 16B

typedef unsigned short ushort_t;
typedef short bf16x8 __attribute__((ext_vector_type(8)));
typedef float f32x4  __attribute__((ext_vector_type(4)));
typedef float f32x16 __attribute__((ext_vector_type(16)));

__device__ __forceinline__ unsigned short f2bf(float f) {
  unsigned int u = __float_as_uint(f);
  u += 0x7FFFu + ((u >> 16) & 1u);
  return (unsigned short)(u >> 16);
}

typedef const __attribute__((address_space(1))) unsigned int* gas_ptr;
typedef __attribute__((address_space(3))) unsigned int* las_ptr;
__device__ __forceinline__ void async_copy16(const void* g, void* l) {
  __builtin_amdgcn_global_load_lds((gas_ptr)g, (las_ptr)l, 16, 0, 0);
}

// swizzled fragment pointer: chunk kc (8 bf16) of LDS row `row`
__device__ __forceinline__ const bf16x8* frag(const ushort_t* t, int row, int kc) {
  return (const bf16x8*)(t + (((row << 4) + (kc ^ (row & 7))) << 3));
}

// ---------------- pre-pass: f32 -> bf16 (+ bias transpose) ----------------
#define QN4 524288    // 16*1024*128/4
#define KN4 1048064   // 16*2047*128/4
#define BN4 32768     // 128*1024/4

__global__ __launch_bounds__(256) void prepass(
    const float* __restrict__ Q, const float* __restrict__ K,
    const float* __restrict__ bias, ushort_t* __restrict__ Qb,
    ushort_t* __restrict__ Kb, ushort_t* __restrict__ bT) {
  int idx = blockIdx.x * 256 + threadIdx.x;
  if (idx < QN4) {
    float4 v = ((const float4*)Q)[idx];
    ((ushort4*)Qb)[idx] = make_ushort4(f2bf(v.x), f2bf(v.y), f2bf(v.z), f2bf(v.w));
  } else if (idx < QN4 + KN4) {
    int i = idx - QN4;
    float4 v = ((const float4*)K)[i];
    ((ushort4*)Kb)[i] = make_ushort4(f2bf(v.x), f2bf(v.y), f2bf(v.z), f2bf(v.w));
  } else if (idx < QN4 + KN4 + BN4) {
    int i = idx - (QN4 + KN4);
    int c = i >> 8;           // 0..127
    int g = i & 255;          // group of 4 along t
    float4 v = ((const float4*)(bias + c * T_))[g];
    int t = g << 2;
    bT[(t + 0) * C_ + c] = f2bf(v.x);
    bT[(t + 1) * C_ + c] = f2bf(v.y);
    bT[(t + 2) * C_ + c] = f2bf(v.z);
    bT[(t + 3) * C_ + c] = f2bf(v.w);
  }
}

// ---------------- main kernel ----------------
// LDS rows (swizzled, 128 bf16 = 16 chunks each):
//   rows 0..31   : Q tile          (A operand)
//   rows 32..127 : K band, 96 rows (B cols 0..95   -> S tiles, waves 0-2)
//   rows 128..191: bias^T, 64 rows (B cols 96..159 -> bias tiles, waves 3-4)
__global__ __launch_bounds__(320) void swmm_main(
    const ushort_t* __restrict__ Qb, const ushort_t* __restrict__ Kb,
    const ushort_t* __restrict__ bT, float* __restrict__ out) {
  __shared__ __align__(16) ushort_t tile[NSLOT * 8];   // 48 KB
  __shared__ __align__(16) float Ss[BW * SS_LD];       // 12.25 KB

  const int b  = blockIdx.z;
  const int w0 = blockIdx.y * BW;
  const int t0 = blockIdx.x * BT;
  const int kbase = w0 + t0;
  const int tid  = threadIdx.x;
  const int wv   = tid >> 6;
  const int lane = tid & 63;

  // ---- stage 3072 x 16B via global_load_lds ----
  for (int slot = tid; slot < NSLOT; slot += 320) {
    int r = slot >> 4;                      // LDS row 0..191
    int c = (slot & 15) ^ (r & 7);          // source chunk (XOR swizzle)
    const ushort_t* g;
    if (r < 32) {
      g = Qb + (((size_t)(b * T_ + w0 + r)) << 7) + (c << 3);
    } else if (r < 128) {
      int gk = kbase + (r - 32);
      if (gk > KT_ - 1) gk = KT_ - 1;       // band col 95 never consumed
      g = Kb + ((size_t)b * KT_ + gk) * C_ + (c << 3);
    } else {
      g = bT + (((size_t)(t0 + r - 128)) << 7) + (c << 3);
    }
    async_copy16(g, &tile[(size_t)(slot - lane) * 8]);  // wave-uniform base
  }
  __syncthreads();

  // ---- fused GEMM: one 32x32 tile per wave, K=128 in 8 steps of 16 ----
  const int half = lane >> 5;               // k half: chunk = 2*s + half
  const int l31  = lane & 31;
  const int n0   = wv * 32;                 // tile col base in combined B space
  const int arow = l31;                     // Q row
  const int brow = (wv < 3) ? (32 + n0 + l31) : (128 + (n0 - 96) + l31);

  f32x16 acc = {};
#pragma unroll
  for (int s = 0; s < 8; ++s) {
    int kc = 2 * s + half;
    bf16x8 a  = *frag(tile, arow, kc);
    bf16x8 bb = *frag(tile, brow, kc);
    acc = __builtin_amdgcn_mfma_f32_32x32x16_bf16(a, bb, acc, 0, 0, 0);
  }

  // ---- waves 0-2: spill S tiles (C/D: col=lane&31, row=(r&3)+8*(r>>2)+4*half)
  if (wv < 3) {
#pragma unroll
    for (int r = 0; r < 16; ++r) {
      int row = (r & 3) + 8 * (r >> 2) + 4 * half;
      Ss[row * SS_LD + n0 + l31] = acc[r];
    }
  }
  __syncthreads();

  // ---- waves 3-4: Z[i,j] = bias_acc[i,j] + S[i, i+j], store ----
  if (wv >= 3) {
    int j = (wv - 3) * 32 + l31;            // 0..63
#pragma unroll
    for (int r = 0; r < 16; ++r) {
      int i = (r & 3) + 8 * (r >> 2) + 4 * half;
      out[(size_t)(b * T_ + w0 + i) * T_ + t0 + j] = acc[r] + Ss[i * SS_LD + i + j];
    }
  }
}

// ---------------- fallback (round-1 style) if ws too small ----------------
#define LDB 136
#define KROWS 96
__global__ __launch_bounds__(256) void swmm_fallback(
    const float* __restrict__ Q, const float* __restrict__ K,
    const float* __restrict__ bias, float* __restrict__ out) {
  __shared__ __align__(16) unsigned short Qs[BW * LDB];
  __shared__ __align__(16) unsigned short Ks[KROWS * LDB];
  __shared__ __align__(16) unsigned short Bs[BT * LDB];
  __shared__ __align__(16) float Ssf[BW * SS_LD];

  const int b   = blockIdx.z;
  const int w0  = blockIdx.y * BW;
  const int t0  = blockIdx.x * BT;
  const int kbase = w0 + t0;
  const int tid = threadIdx.x;

  {
    const float4* src = (const float4*)(Q + (size_t)(b * T_ + w0) * C_);
    for (int v = tid; v < BW * (C_ / 4); v += 256) {
      int r = v >> 5, cc = v & 31;
      float4 q = src[r * 32 + cc];
      unsigned short* d = &Qs[r * LDB + (cc << 2)];
      d[0] = f2bf(q.x); d[1] = f2bf(q.y); d[2] = f2bf(q.z); d[3] = f2bf(q.w);
    }
  }
  {
    for (int v = tid; v < KROWS * (C_ / 4); v += 256) {
      int r = v >> 5, cc = v & 31;
      int g = kbase + r;
      float4 kv = make_float4(0.f, 0.f, 0.f, 0.f);
      if (g < KT_) kv = ((const float4*)(K + ((size_t)b * KT_ + g) * C_))[cc];
      unsigned short* d = &Ks[r * LDB + (cc << 2)];
      d[0] = f2bf(kv.x); d[1] = f2bf(kv.y); d[2] = f2bf(kv.z); d[3] = f2bf(kv.w);
    }
  }
  {
    for (int v = tid; v < C_ * (BT / 4); v += 256) {
      int c = v >> 4, jj = v & 15;
      float4 bv = ((const float4*)(bias + (size_t)c * T_ + t0))[jj];
      int j4 = jj << 2;
      Bs[(j4 + 0) * LDB + c] = f2bf(bv.x);
      Bs[(j4 + 1) * LDB + c] = f2bf(bv.y);
      Bs[(j4 + 2) * LDB + c] = f2bf(bv.z);
      Bs[(j4 + 3) * LDB + c] = f2bf(bv.w);
    }
  }
  __syncthreads();

  const int wv    = tid >> 6;
  const int lane  = tid & 63;
  const int frow  = lane & 15;
  const int koff  = (lane >> 4) * 8;
  const int drow4 = (lane >> 4) * 4;
  const int NS = KROWS / 16;

  for (int s = wv; s < 2 * NS; s += 4) {
    int mb = s / NS, nn = s % NS;
    int m0 = mb * 16, nn0 = nn * 16;
    const unsigned short* arow = &Qs[(m0 + frow) * LDB + koff];
    const unsigned short* brow = &Ks[(nn0 + frow) * LDB + koff];
    f32x4 acc = {0.f, 0.f, 0.f, 0.f};
#pragma unroll
    for (int k0 = 0; k0 < C_; k0 += 32) {
      bf16x8 a  = *(const bf16x8*)(arow + k0);
      bf16x8 bb = *(const bf16x8*)(brow + k0);
      acc = __builtin_amdgcn_mfma_f32_16x16x32_bf16(a, bb, acc, 0, 0, 0);
    }
#pragma unroll
    for (int r = 0; r < 4; ++r)
      Ssf[(m0 + drow4 + r) * SS_LD + nn0 + frow] = acc[r];
  }

  f32x4 bacc[2];
#pragma unroll
  for (int q = 0; q < 2; ++q) {
    int idx = wv + q * 4;
    int m0 = (idx >> 2) * 16, j0 = (idx & 3) * 16;
    const unsigned short* arow = &Qs[(m0 + frow) * LDB + koff];
    const unsigned short* brow = &Bs[(j0 + frow) * LDB + koff];
    f32x4 acc = {0.f, 0.f, 0.f, 0.f};
#pragma unroll
    for (int k0 = 0; k0 < C_; k0 += 32) {
      bf16x8 a  = *(const bf16x8*)(arow + k0);
      bf16x8 bb = *(const bf16x8*)(brow + k0);
      acc = __builtin_amdgcn_mfma_f32_16x16x32_bf16(a, bb, acc, 0, 0, 0);
    }
    bacc[q] = acc;
  }
  __syncthreads();

#pragma unroll
  for (int q = 0; q < 2; ++q) {
    int idx = wv + q * 4;
    int m0 = (idx >> 2) * 16, j0 = (idx & 3) * 16;
#pragma unroll
    for (int r = 0; r < 4; ++r) {
      int i = m0 + drow4 + r;
      int j = j0 + frow;
      out[(size_t)(b * T_ + w0 + i) * T_ + t0 + j] = bacc[q][r] + Ssf[i * SS_LD + i + j];
    }
  }
}

extern "C" void kernel_launch(void* const* d_in, const int* in_sizes, int n_in,
                              void* d_out, int out_size, void* d_ws, size_t ws_size,
                              hipStream_t stream) {
  const float* Q    = (const float*)d_in[0];
  const float* K    = (const float*)d_in[1];
  const float* bias = (const float*)d_in[2];
  float* out = (float*)d_out;

  const size_t QB = (size_t)B_ * T_ * C_ * 2;        // 4 MB
  const size_t KB = (size_t)B_ * KT_ * C_ * 2;       // 8.38 MB
  const size_t TB = (size_t)T_ * C_ * 2;             // 0.25 MB
  dim3 grid(T_ / BT, T_ / BW, B_);                   // (16, 32, 16)

  if (ws_size >= QB + KB + TB) {
    ushort_t* Qb = (ushort_t*)d_ws;
    ushort_t* Kb = (ushort_t*)((char*)d_ws + QB);
    ushort_t* bT = (ushort_t*)((char*)d_ws + QB + KB);
    prepass<<<(QN4 + KN4 + BN4) / 256, 256, 0, stream>>>(Q, K, bias, Qb, Kb, bT);
    swmm_main<<<grid, dim3(320), 0, stream>>>(Qb, Kb, bT, out);
  } else {
    swmm_fallback<<<grid, dim3(256), 0, stream>>>(Q, K, bias, out);
  }
}

// Round 4
// 134.677 us; speedup vs baseline: 1.1013x; 1.1013x over previous
//
#include <hip/hip_runtime.h>
#include <hip/hip_bf16.h>

// Z[b,w,t] = sum_c Q[b,w,c] * (K[b,w+t,c] + bias[c,t])
// B=16, T=1024, C=128, K has 2T-1=2047 rows.
//
// Round 4: persistent w-loop. Grid 512 blocks (16 t-tiles x 2 w-segs x 16 b),
// each block does 16 w-iterations of the fused 5-tile mfma_32x32x16 GEMM:
//   - bias^T tile staged once (16 KB)
//   - K band in a 128-row circular LDS buffer; slides 32 rows/iter (8 KB/iter)
//   - Q tile double-buffered (8 KB/iter), prefetched 1 iter ahead
// Prefetch issued AFTER the loop-top barrier so the barrier only drains the
// previous iteration's loads; compute overlaps delivery.

#define B_    16
#define T_    1024
#define C_    128
#define KT_   2047

#define BW    32
#define BT    64
#define SS_LD 98

typedef unsigned short ushort_t;
typedef short bf16x8 __attribute__((ext_vector_type(8)));
typedef float f32x4  __attribute__((ext_vector_type(4)));
typedef float f32x16 __attribute__((ext_vector_type(16)));

__device__ __forceinline__ unsigned short f2bf(float f) {
  unsigned int u = __float_as_uint(f);
  u += 0x7FFFu + ((u >> 16) & 1u);
  return (unsigned short)(u >> 16);
}

typedef const __attribute__((address_space(1))) unsigned int* gas_ptr;
typedef __attribute__((address_space(3))) unsigned int* las_ptr;
__device__ __forceinline__ void async_copy16(const void* g, void* l) {
  __builtin_amdgcn_global_load_lds((gas_ptr)g, (las_ptr)l, 16, 0, 0);
}

// swizzled fragment pointer: chunk kc (8 bf16) of LDS row `row`
// (row in [0,256): 0..127 K circular, 128..191 Q double-buf, 192..255 bias)
__device__ __forceinline__ const bf16x8* frag(const ushort_t* t, int row, int kc) {
  return (const bf16x8*)(t + (((row << 4) + (kc ^ (row & 7))) << 3));
}

// ---------------- pre-pass: f32 -> bf16 (+ bias transpose) ----------------
#define QN4 524288    // 16*1024*128/4
#define KN4 1048064   // 16*2047*128/4
#define BN4 32768     // 128*1024/4

__global__ __launch_bounds__(256) void prepass(
    const float* __restrict__ Q, const float* __restrict__ K,
    const float* __restrict__ bias, ushort_t* __restrict__ Qb,
    ushort_t* __restrict__ Kb, ushort_t* __restrict__ bT) {
  int idx = blockIdx.x * 256 + threadIdx.x;
  if (idx < QN4) {
    float4 v = ((const float4*)Q)[idx];
    ((ushort4*)Qb)[idx] = make_ushort4(f2bf(v.x), f2bf(v.y), f2bf(v.z), f2bf(v.w));
  } else if (idx < QN4 + KN4) {
    int i = idx - QN4;
    float4 v = ((const float4*)K)[i];
    ((ushort4*)Kb)[i] = make_ushort4(f2bf(v.x), f2bf(v.y), f2bf(v.z), f2bf(v.w));
  } else if (idx < QN4 + KN4 + BN4) {
    int i = idx - (QN4 + KN4);
    int c = i >> 8;           // 0..127
    int g = i & 255;          // group of 4 along t
    float4 v = ((const float4*)(bias + c * T_))[g];
    int t = g << 2;
    bT[(t + 0) * C_ + c] = f2bf(v.x);
    bT[(t + 1) * C_ + c] = f2bf(v.y);
    bT[(t + 2) * C_ + c] = f2bf(v.z);
    bT[(t + 3) * C_ + c] = f2bf(v.w);
  }
}

// ---------------- main kernel ----------------
__global__ __launch_bounds__(320) void swmm_main(
    const ushort_t* __restrict__ Qb, const ushort_t* __restrict__ Kb,
    const ushort_t* __restrict__ bT, float* __restrict__ out) {
  __shared__ __align__(16) ushort_t tile[4096 * 8];   // 64 KB (256 rows x 128 bf16)
  __shared__ __align__(16) float Ss[BW * SS_LD];      // 12.25 KB

  const int b     = blockIdx.z;
  const int wseg  = blockIdx.y;
  const int t0    = blockIdx.x * BT;
  const int wbase = wseg * 512;
  const int g0    = t0 + wbase;               // band base, iter 0 (mod 32 == 0)
  const int tid   = threadIdx.x;
  const int wv    = tid >> 6;
  const int lane  = tid & 63;
  const int lrow  = lane >> 4;                // row within a 4-row chunk
  const int p     = lane & 15;                // dest chunk position in row

  const ushort_t* Kbase = Kb + ((size_t)b * KT_) * C_;
  const ushort_t* Qbase = Qb + ((size_t)b * T_) * C_;

  // ---- prologue: K[g0,g0+96) (24 chunks), Q iter0 (8), bias (16) = 48 ----
  for (int k = 0; k < 10; ++k) {
    int ch = k * 5 + wv;
    if (ch >= 48) break;                      // wave-uniform
    if (ch < 24) {
      int r0 = ch * 4;
      int g  = g0 + r0 + lrow;
      int c  = p ^ (g & 7);
      int ga = g > KT_ - 1 ? KT_ - 1 : g;     // band col 95 never consumed
      async_copy16(Kbase + (size_t)ga * C_ + (c << 3),
                   &tile[(size_t)(((g0 + r0) & 127) << 7)]);
    } else if (ch < 32) {
      int qr0 = (ch - 24) * 4;
      int qr  = qr0 + lrow;
      int c   = p ^ (qr & 7);
      async_copy16(Qbase + (size_t)(wbase + qr) * C_ + (c << 3),
                   &tile[(size_t)((128 + qr0) << 7)]);
    } else {
      int j0 = (ch - 32) * 4;
      int j  = j0 + lrow;
      int c  = p ^ (j & 7);
      async_copy16(bT + (size_t)(t0 + j) * C_ + (c << 3),
                   &tile[(size_t)((192 + j0) << 7)]);
    }
  }

  const int half = lane >> 5;
  const int l31  = lane & 31;

  for (int i = 0; i < 16; ++i) {
    const int w0 = wbase + (i << 5);
    const int gi = g0 + (i << 5);
    __syncthreads();    // iter-i data resident (drains loads issued earlier)

    // ---- prefetch iter i+1: Q -> other buf (8 chunks), K 32 rows (8) ----
    if (i < 15) {
      for (int k = 0; k < 4; ++k) {
        int ch = k * 5 + wv;
        if (ch >= 16) break;                  // wave-uniform
        if (ch < 8) {
          int qr0 = ch * 4;
          int qr  = qr0 + lrow;
          int c   = p ^ (qr & 7);
          async_copy16(Qbase + (size_t)(w0 + 32 + qr) * C_ + (c << 3),
                       &tile[(size_t)((128 + (((i + 1) & 1) << 5) + qr0) << 7)]);
        } else {
          int r0 = (ch - 8) * 4;
          int g  = gi + 96 + r0 + lrow;
          int c  = p ^ (g & 7);
          int ga = g > KT_ - 1 ? KT_ - 1 : g;
          async_copy16(Kbase + (size_t)ga * C_ + (c << 3),
                       &tile[(size_t)(((gi + 96 + r0) & 127) << 7)]);
        }
      }
    }

    // ---- fused GEMM: one 32x32 tile per wave, K=128 in 8 steps ----
    const int Arow = 128 + ((i & 1) << 5) + l31;
    const int Brow = (wv < 3) ? ((gi + (wv << 5) + l31) & 127)
                              : (192 + ((wv - 3) << 5) + l31);
    f32x16 acc = {};
#pragma unroll
    for (int s = 0; s < 8; ++s) {
      int kc = 2 * s + half;
      bf16x8 a  = *frag(tile, Arow, kc);
      bf16x8 bb = *frag(tile, Brow, kc);
      acc = __builtin_amdgcn_mfma_f32_32x32x16_bf16(a, bb, acc, 0, 0, 0);
    }

    // ---- waves 0-2: spill S tiles to Ss ----
    if (wv < 3) {
      int n0 = wv << 5;
#pragma unroll
      for (int r = 0; r < 16; ++r) {
        int row = (r & 3) + 8 * (r >> 2) + 4 * half;
        Ss[row * SS_LD + n0 + l31] = acc[r];
      }
    }
    __syncthreads();    // Ss ready (also drains prefetch; overlapped w/ compute)

    // ---- waves 3-4: Z[i',j] = bias_acc + S[i', i'+j], store ----
    if (wv >= 3) {
      int j = ((wv - 3) << 5) + l31;
      float* orow = out + (size_t)(b * T_ + w0) * T_ + t0 + j;
#pragma unroll
      for (int r = 0; r < 16; ++r) {
        int irow = (r & 3) + 8 * (r >> 2) + 4 * half;
        orow[(size_t)irow * T_] = acc[r] + Ss[irow * SS_LD + irow + j];
      }
    }
  }
}

// ---------------- fallback (round-1 style) if ws too small ----------------
#define LDB 136
#define KROWS 96
__global__ __launch_bounds__(256) void swmm_fallback(
    const float* __restrict__ Q, const float* __restrict__ K,
    const float* __restrict__ bias, float* __restrict__ out) {
  __shared__ __align__(16) unsigned short Qs[BW * LDB];
  __shared__ __align__(16) unsigned short Ks[KROWS * LDB];
  __shared__ __align__(16) unsigned short Bs[BT * LDB];
  __shared__ __align__(16) float Ssf[BW * SS_LD];

  const int b   = blockIdx.z;
  const int w0  = blockIdx.y * BW;
  const int t0  = blockIdx.x * BT;
  const int kbase = w0 + t0;
  const int tid = threadIdx.x;

  {
    const float4* src = (const float4*)(Q + (size_t)(b * T_ + w0) * C_);
    for (int v = tid; v < BW * (C_ / 4); v += 256) {
      int r = v >> 5, cc = v & 31;
      float4 q = src[r * 32 + cc];
      unsigned short* d = &Qs[r * LDB + (cc << 2)];
      d[0] = f2bf(q.x); d[1] = f2bf(q.y); d[2] = f2bf(q.z); d[3] = f2bf(q.w);
    }
  }
  {
    for (int v = tid; v < KROWS * (C_ / 4); v += 256) {
      int r = v >> 5, cc = v & 31;
      int g = kbase + r;
      float4 kv = make_float4(0.f, 0.f, 0.f, 0.f);
      if (g < KT_) kv = ((const float4*)(K + ((size_t)b * KT_ + g) * C_))[cc];
      unsigned short* d = &Ks[r * LDB + (cc << 2)];
      d[0] = f2bf(kv.x); d[1] = f2bf(kv.y); d[2] = f2bf(kv.z); d[3] = f2bf(kv.w);
    }
  }
  {
    for (int v = tid; v < C_ * (BT / 4); v += 256) {
      int c = v >> 4, jj = v & 15;
      float4 bv = ((const float4*)(bias + (size_t)c * T_ + t0))[jj];
      int j4 = jj << 2;
      Bs[(j4 + 0) * LDB + c] = f2bf(bv.x);
      Bs[(j4 + 1) * LDB + c] = f2bf(bv.y);
      Bs[(j4 + 2) * LDB + c] = f2bf(bv.z);
      Bs[(j4 + 3) * LDB + c] = f2bf(bv.w);
    }
  }
  __syncthreads();

  const int wv    = tid >> 6;
  const int lane  = tid & 63;
  const int frow  = lane & 15;
  const int koff  = (lane >> 4) * 8;
  const int drow4 = (lane >> 4) * 4;
  const int NS = KROWS / 16;

  for (int s = wv; s < 2 * NS; s += 4) {
    int mb = s / NS, nn = s % NS;
    int m0 = mb * 16, nn0 = nn * 16;
    const unsigned short* arow = &Qs[(m0 + frow) * LDB + koff];
    const unsigned short* brow = &Ks[(nn0 + frow) * LDB + koff];
    f32x4 acc = {0.f, 0.f, 0.f, 0.f};
#pragma unroll
    for (int k0 = 0; k0 < C_; k0 += 32) {
      bf16x8 a  = *(const bf16x8*)(arow + k0);
      bf16x8 bb = *(const bf16x8*)(brow + k0);
      acc = __builtin_amdgcn_mfma_f32_16x16x32_bf16(a, bb, acc, 0, 0, 0);
    }
#pragma unroll
    for (int r = 0; r < 4; ++r)
      Ssf[(m0 + drow4 + r) * SS_LD + nn0 + frow] = acc[r];
  }

  f32x4 bacc[2];
#pragma unroll
  for (int q = 0; q < 2; ++q) {
    int idx = wv + q * 4;
    int m0 = (idx >> 2) * 16, j0 = (idx & 3) * 16;
    const unsigned short* arow = &Qs[(m0 + frow) * LDB + koff];
    const unsigned short* brow = &Bs[(j0 + frow) * LDB + koff];
    f32x4 acc = {0.f, 0.f, 0.f, 0.f};
#pragma unroll
    for (int k0 = 0; k0 < C_; k0 += 32) {
      bf16x8 a  = *(const bf16x8*)(arow + k0);
      bf16x8 bb = *(const bf16x8*)(brow + k0);
      acc = __builtin_amdgcn_mfma_f32_16x16x32_bf16(a, bb, acc, 0, 0, 0);
    }
    bacc[q] = acc;
  }
  __syncthreads();

#pragma unroll
  for (int q = 0; q < 2; ++q) {
    int idx = wv + q * 4;
    int m0 = (idx >> 2) * 16, j0 = (idx & 3) * 16;
#pragma unroll
    for (int r = 0; r < 4; ++r) {
      int i = m0 + drow4 + r;
      int j = j0 + frow;
      out[(size_t)(b * T_ + w0 + i) * T_ + t0 + j] = bacc[q][r] + Ssf[i * SS_LD + i + j];
    }
  }
}

extern "C" void kernel_launch(void* const* d_in, const int* in_sizes, int n_in,
                              void* d_out, int out_size, void* d_ws, size_t ws_size,
                              hipStream_t stream) {
  const float* Q    = (const float*)d_in[0];
  const float* K    = (const float*)d_in[1];
  const float* bias = (const float*)d_in[2];
  float* out = (float*)d_out;

  const size_t QB = (size_t)B_ * T_ * C_ * 2;        // 4 MB
  const size_t KB = (size_t)B_ * KT_ * C_ * 2;       // 8.38 MB
  const size_t TB = (size_t)T_ * C_ * 2;             // 0.25 MB

  if (ws_size >= QB + KB + TB) {
    ushort_t* Qb = (ushort_t*)d_ws;
    ushort_t* Kb = (ushort_t*)((char*)d_ws + QB);
    ushort_t* bT = (ushort_t*)((char*)d_ws + QB + KB);
    prepass<<<(QN4 + KN4 + BN4) / 256, 256, 0, stream>>>(Q, K, bias, Qb, Kb, bT);
    swmm_main<<<dim3(T_ / BT, 2, B_), dim3(320), 0, stream>>>(Qb, Kb, bT, out);
  } else {
    swmm_fallback<<<dim3(T_ / BT, T_ / BW, B_), dim3(256), 0, stream>>>(Q, K, bias, out);
  }
}

// Round 5
// 127.418 us; speedup vs baseline: 1.1641x; 1.0570x over previous
//
#include <hip/hip_runtime.h>
#include <hip/hip_bf16.h>

// Z[b,w,t] = sum_c Q[b,w,c] * (K[b,w+t,c] + bias[c,t])
// B=16, T=1024, C=128, K has 2T-1=2047 rows.
//
// Round 5: persistent w-loop, ONE barrier per iteration.
//   - bias^T B-fragments held in VGPRs (waves 3-4), loaded once from global
//   - Ss (f32 band scores) double-buffered; waves 3-4 consume iter i-1's Ss
//     (+ bias acc held in regs) while waves 0-2 produce iter i's -> no
//     intra-iter producer/consumer barrier
//   - K band in a 128-row circular LDS buffer (slides 32 rows/iter), Q tile
//     double-buffered; both prefetched a FULL iteration ahead, so the
//     top-of-loop barrier's vmcnt drain is covered by compute+store work.

#define B_    16
#define T_    1024
#define C_    128
#define KT_   2047

#define BW    32
#define BT    64
#define SS_LD 98

typedef unsigned short ushort_t;
typedef short bf16x8 __attribute__((ext_vector_type(8)));
typedef float f32x4  __attribute__((ext_vector_type(4)));
typedef float f32x16 __attribute__((ext_vector_type(16)));

__device__ __forceinline__ unsigned short f2bf(float f) {
  unsigned int u = __float_as_uint(f);
  u += 0x7FFFu + ((u >> 16) & 1u);
  return (unsigned short)(u >> 16);
}

typedef const __attribute__((address_space(1))) unsigned int* gas_ptr;
typedef __attribute__((address_space(3))) unsigned int* las_ptr;
__device__ __forceinline__ void async_copy16(const void* g, void* l) {
  __builtin_amdgcn_global_load_lds((gas_ptr)g, (las_ptr)l, 16, 0, 0);
}

// swizzled fragment pointer: chunk kc (8 bf16) of LDS row `row`
// rows 0..127: K circular (row = g & 127); rows 128..191: Q double buffer
__device__ __forceinline__ const bf16x8* frag(const ushort_t* t, int row, int kc) {
  return (const bf16x8*)(t + (((row << 4) + (kc ^ (row & 7))) << 3));
}

// ---------------- pre-pass: f32 -> bf16 (+ bias transpose) ----------------
#define QN4 524288    // 16*1024*128/4
#define KN4 1048064   // 16*2047*128/4
#define BN4 32768     // 128*1024/4

__global__ __launch_bounds__(256) void prepass(
    const float* __restrict__ Q, const float* __restrict__ K,
    const float* __restrict__ bias, ushort_t* __restrict__ Qb,
    ushort_t* __restrict__ Kb, ushort_t* __restrict__ bT) {
  int idx = blockIdx.x * 256 + threadIdx.x;
  if (idx < QN4) {
    float4 v = ((const float4*)Q)[idx];
    ((ushort4*)Qb)[idx] = make_ushort4(f2bf(v.x), f2bf(v.y), f2bf(v.z), f2bf(v.w));
  } else if (idx < QN4 + KN4) {
    int i = idx - QN4;
    float4 v = ((const float4*)K)[i];
    ((ushort4*)Kb)[i] = make_ushort4(f2bf(v.x), f2bf(v.y), f2bf(v.z), f2bf(v.w));
  } else if (idx < QN4 + KN4 + BN4) {
    int i = idx - (QN4 + KN4);
    int c = i >> 8;           // 0..127
    int g = i & 255;          // group of 4 along t
    float4 v = ((const float4*)(bias + c * T_))[g];
    int t = g << 2;
    bT[(t + 0) * C_ + c] = f2bf(v.x);
    bT[(t + 1) * C_ + c] = f2bf(v.y);
    bT[(t + 2) * C_ + c] = f2bf(v.z);
    bT[(t + 3) * C_ + c] = f2bf(v.w);
  }
}

// ---------------- main kernel ----------------
__global__ __launch_bounds__(320) void swmm_main(
    const ushort_t* __restrict__ Qb, const ushort_t* __restrict__ Kb,
    const ushort_t* __restrict__ bT, float* __restrict__ out) {
  __shared__ __align__(16) ushort_t tile[192 * 128];   // 48 KB
  __shared__ __align__(16) float Ss[2][BW * SS_LD];    // 24.5 KB

  const int b     = blockIdx.z;
  const int wseg  = blockIdx.y;
  const int t0    = blockIdx.x * BT;
  const int wbase = wseg * 512;
  const int g0    = t0 + wbase;
  const int tid   = threadIdx.x;
  const int wv    = tid >> 6;
  const int lane  = tid & 63;
  const int lrow  = lane >> 4;
  const int p     = lane & 15;
  const int half  = lane >> 5;
  const int l31   = lane & 31;

  const ushort_t* Kbase = Kb + (size_t)b * KT_ * C_;
  const ushort_t* Qbase = Qb + (size_t)b * T_ * C_;

  // ---- bias B-fragments in regs (waves 3-4), loaded once; bias is L2-hot ----
  bf16x8 bfrag[8];
  if (wv >= 3) {
    const ushort_t* brow = bT + (size_t)(t0 + ((wv - 3) << 5) + l31) * C_;
#pragma unroll
    for (int s = 0; s < 8; ++s)
      bfrag[s] = *(const bf16x8*)(brow + ((2 * s + half) << 3));
  }

  // ---- prologue staging: K[g0,g0+96) (24 chunks) + Q iter0 (8 chunks) ----
  for (int k = 0; k < 7; ++k) {
    int ch = k * 5 + wv;
    if (ch >= 32) break;                      // wave-uniform
    if (ch < 24) {
      int r0 = ch * 4;
      int g  = g0 + r0 + lrow;
      int c  = p ^ (g & 7);
      int ga = g > KT_ - 1 ? KT_ - 1 : g;     // band col 95 never consumed
      async_copy16(Kbase + (size_t)ga * C_ + (c << 3),
                   &tile[(size_t)((g0 + r0) & 127) << 7]);
    } else {
      int qr0 = (ch - 24) * 4;
      int qr  = qr0 + lrow;
      int c   = p ^ (qr & 7);
      async_copy16(Qbase + (size_t)(wbase + qr) * C_ + (c << 3),
                   &tile[(size_t)(128 + qr0) << 7]);
    }
  }

  f32x16 pacc = {};

  for (int i = 0; i < 16; ++i) {
    const int w0 = wbase + (i << 5);
    const int gi = g0 + (i << 5);
    __syncthreads();   // iter-i K/Q resident; iter i-1's Ss complete

    // ---- prefetch iter i+1: 8 Q chunks -> other buf, 8 K chunks (32 rows) ----
    if (i < 15) {
      for (int k = 0; k < 4; ++k) {
        int ch = k * 5 + wv;
        if (ch >= 16) break;                  // wave-uniform
        if (ch < 8) {
          int qr0 = ch * 4;
          int qr  = qr0 + lrow;
          int c   = p ^ (qr & 7);
          async_copy16(Qbase + (size_t)(w0 + 32 + qr) * C_ + (c << 3),
                       &tile[(size_t)(128 + (((i + 1) & 1) << 5) + qr0) << 7]);
        } else {
          int r0 = (ch - 8) * 4;
          int g  = gi + 96 + r0 + lrow;
          int c  = p ^ (g & 7);
          int ga = g > KT_ - 1 ? KT_ - 1 : g;
          async_copy16(Kbase + (size_t)ga * C_ + (c << 3),
                       &tile[(size_t)((gi + 96 + r0) & 127) << 7]);
        }
      }
    }

    const int Arow = 128 + ((i & 1) << 5) + l31;

    if (wv < 3) {
      // ---- produce S tiles for iter i -> Ss[i&1] ----
      const int Brow = (gi + (wv << 5) + l31) & 127;
      f32x16 acc = {};
#pragma unroll
      for (int s = 0; s < 8; ++s) {
        int kc = 2 * s + half;
        acc = __builtin_amdgcn_mfma_f32_32x32x16_bf16(
            *frag(tile, Arow, kc), *frag(tile, Brow, kc), acc, 0, 0, 0);
      }
      const int n0 = wv << 5;
      float* Sd = Ss[i & 1];
#pragma unroll
      for (int r = 0; r < 16; ++r) {
        int row = (r & 3) + 8 * (r >> 2) + 4 * half;
        Sd[row * SS_LD + n0 + l31] = acc[r];
      }
    } else {
      // ---- consume iter i-1: Z = pacc + diag-gather(Ss[(i-1)&1]) ----
      if (i > 0) {
        const float* Sp = Ss[(i - 1) & 1];
        const int j = ((wv - 3) << 5) + l31;
        float* orow = out + (size_t)(b * T_ + (w0 - 32)) * T_ + t0 + j;
#pragma unroll
        for (int r = 0; r < 16; ++r) {
          int irow = (r & 3) + 8 * (r >> 2) + 4 * half;
          orow[(size_t)irow * T_] = pacc[r] + Sp[irow * SS_LD + irow + j];
        }
      }
      // ---- produce bias acc for iter i (held until iter i+1) ----
      f32x16 acc = {};
#pragma unroll
      for (int s = 0; s < 8; ++s) {
        int kc = 2 * s + half;
        acc = __builtin_amdgcn_mfma_f32_32x32x16_bf16(
            *frag(tile, Arow, kc), bfrag[s], acc, 0, 0, 0);
      }
      pacc = acc;
    }
  }

  // ---- epilogue: consume iter 15 ----
  __syncthreads();
  if (wv >= 3) {
    const float* Sp = Ss[1];                  // 15 & 1
    const int j = ((wv - 3) << 5) + l31;
    float* orow = out + (size_t)(b * T_ + wbase + 480) * T_ + t0 + j;
#pragma unroll
    for (int r = 0; r < 16; ++r) {
      int irow = (r & 3) + 8 * (r >> 2) + 4 * half;
      orow[(size_t)irow * T_] = pacc[r] + Sp[irow * SS_LD + irow + j];
    }
  }
}

// ---------------- fallback (round-1 style) if ws too small ----------------
#define LDB 136
#define KROWS 96
__global__ __launch_bounds__(256) void swmm_fallback(
    const float* __restrict__ Q, const float* __restrict__ K,
    const float* __restrict__ bias, float* __restrict__ out) {
  __shared__ __align__(16) unsigned short Qs[BW * LDB];
  __shared__ __align__(16) unsigned short Ks[KROWS * LDB];
  __shared__ __align__(16) unsigned short Bs[BT * LDB];
  __shared__ __align__(16) float Ssf[BW * SS_LD];

  const int b   = blockIdx.z;
  const int w0  = blockIdx.y * BW;
  const int t0  = blockIdx.x * BT;
  const int kbase = w0 + t0;
  const int tid = threadIdx.x;

  {
    const float4* src = (const float4*)(Q + (size_t)(b * T_ + w0) * C_);
    for (int v = tid; v < BW * (C_ / 4); v += 256) {
      int r = v >> 5, cc = v & 31;
      float4 q = src[r * 32 + cc];
      unsigned short* d = &Qs[r * LDB + (cc << 2)];
      d[0] = f2bf(q.x); d[1] = f2bf(q.y); d[2] = f2bf(q.z); d[3] = f2bf(q.w);
    }
  }
  {
    for (int v = tid; v < KROWS * (C_ / 4); v += 256) {
      int r = v >> 5, cc = v & 31;
      int g = kbase + r;
      float4 kv = make_float4(0.f, 0.f, 0.f, 0.f);
      if (g < KT_) kv = ((const float4*)(K + ((size_t)b * KT_ + g) * C_))[cc];
      unsigned short* d = &Ks[r * LDB + (cc << 2)];
      d[0] = f2bf(kv.x); d[1] = f2bf(kv.y); d[2] = f2bf(kv.z); d[3] = f2bf(kv.w);
    }
  }
  {
    for (int v = tid; v < C_ * (BT / 4); v += 256) {
      int c = v >> 4, jj = v & 15;
      float4 bv = ((const float4*)(bias + (size_t)c * T_ + t0))[jj];
      int j4 = jj << 2;
      Bs[(j4 + 0) * LDB + c] = f2bf(bv.x);
      Bs[(j4 + 1) * LDB + c] = f2bf(bv.y);
      Bs[(j4 + 2) * LDB + c] = f2bf(bv.z);
      Bs[(j4 + 3) * LDB + c] = f2bf(bv.w);
    }
  }
  __syncthreads();

  const int wv    = tid >> 6;
  const int lane  = tid & 63;
  const int frow  = lane & 15;
  const int koff  = (lane >> 4) * 8;
  const int drow4 = (lane >> 4) * 4;
  const int NS = KROWS / 16;

  for (int s = wv; s < 2 * NS; s += 4) {
    int mb = s / NS, nn = s % NS;
    int m0 = mb * 16, nn0 = nn * 16;
    const unsigned short* arow = &Qs[(m0 + frow) * LDB + koff];
    const unsigned short* brow = &Ks[(nn0 + frow) * LDB + koff];
    f32x4 acc = {0.f, 0.f, 0.f, 0.f};
#pragma unroll
    for (int k0 = 0; k0 < C_; k0 += 32) {
      bf16x8 a  = *(const bf16x8*)(arow + k0);
      bf16x8 bb = *(const bf16x8*)(brow + k0);
      acc = __builtin_amdgcn_mfma_f32_16x16x32_bf16(a, bb, acc, 0, 0, 0);
    }
#pragma unroll
    for (int r = 0; r < 4; ++r)
      Ssf[(m0 + drow4 + r) * SS_LD + nn0 + frow] = acc[r];
  }

  f32x4 bacc[2];
#pragma unroll
  for (int q = 0; q < 2; ++q) {
    int idx = wv + q * 4;
    int m0 = (idx >> 2) * 16, j0 = (idx & 3) * 16;
    const unsigned short* arow = &Qs[(m0 + frow) * LDB + koff];
    const unsigned short* brow = &Bs[(j0 + frow) * LDB + koff];
    f32x4 acc = {0.f, 0.f, 0.f, 0.f};
#pragma unroll
    for (int k0 = 0; k0 < C_; k0 += 32) {
      bf16x8 a  = *(const bf16x8*)(arow + k0);
      bf16x8 bb = *(const bf16x8*)(brow + k0);
      acc = __builtin_amdgcn_mfma_f32_16x16x32_bf16(a, bb, acc, 0, 0, 0);
    }
    bacc[q] = acc;
  }
  __syncthreads();

#pragma unroll
  for (int q = 0; q < 2; ++q) {
    int idx = wv + q * 4;
    int m0 = (idx >> 2) * 16, j0 = (idx & 3) * 16;
#pragma unroll
    for (int r = 0; r < 4; ++r) {
      int i = m0 + drow4 + r;
      int j = j0 + frow;
      out[(size_t)(b * T_ + w0 + i) * T_ + t0 + j] = bacc[q][r] + Ssf[i * SS_LD + i + j];
    }
  }
}

extern "C" void kernel_launch(void* const* d_in, const int* in_sizes, int n_in,
                              void* d_out, int out_size, void* d_ws, size_t ws_size,
                              hipStream_t stream) {
  const float* Q    = (const float*)d_in[0];
  const float* K    = (const float*)d_in[1];
  const float* bias = (const float*)d_in[2];
  float* out = (float*)d_out;

  const size_t QB = (size_t)B_ * T_ * C_ * 2;        // 4 MB
  const size_t KB = (size_t)B_ * KT_ * C_ * 2;       // 8.38 MB
  const size_t TB = (size_t)T_ * C_ * 2;             // 0.25 MB

  if (ws_size >= QB + KB + TB) {
    ushort_t* Qb = (ushort_t*)d_ws;
    ushort_t* Kb = (ushort_t*)((char*)d_ws + QB);
    ushort_t* bT = (ushort_t*)((char*)d_ws + QB + KB);
    prepass<<<(QN4 + KN4 + BN4) / 256, 256, 0, stream>>>(Q, K, bias, Qb, Kb, bT);
    swmm_main<<<dim3(T_ / BT, 2, B_), dim3(320), 0, stream>>>(Qb, Kb, bT, out);
  } else {
    swmm_fallback<<<dim3(T_ / BT, T_ / BW, B_), dim3(256), 0, stream>>>(Q, K, bias, out);
  }
}